// Round 1
// baseline (231.604 us; speedup 1.0000x reference)
//
#include <hip/hip_runtime.h>
#include <hip/hip_bf16.h>
#include <stdint.h>

#define NB 8
#define NSQ 1024
#define NSK 1024
#define NHID 512
#define NHEAD 4
#define NDH 128

typedef __attribute__((ext_vector_type(8))) short short8;
typedef __attribute__((ext_vector_type(4))) float f32x4;

__device__ __forceinline__ unsigned short f2b(float f) {
  unsigned int u = __builtin_bit_cast(unsigned int, f);
  u = u + 0x7FFFu + ((u >> 16) & 1u);
  return (unsigned short)(u >> 16);
}

// ---------------- K0: f32 -> bf16 convert (vectorized, 8 elems/thread) ----
__global__ void cvt_kernel(const float* __restrict__ src,
                           unsigned short* __restrict__ dst, int n) {
  int i = (blockIdx.x * blockDim.x + threadIdx.x) * 8;
  if (i >= n) return;
  float4 a = *(const float4*)(src + i);
  float4 b = *(const float4*)(src + i + 4);
  short8 o;
  o[0] = (short)f2b(a.x); o[1] = (short)f2b(a.y);
  o[2] = (short)f2b(a.z); o[3] = (short)f2b(a.w);
  o[4] = (short)f2b(b.x); o[5] = (short)f2b(b.y);
  o[6] = (short)f2b(b.z); o[7] = (short)f2b(b.w);
  *(short8*)(dst + i) = o;
}

// ---------------- K1: C[m,n] = sum_k A[m,k]*W[n,k]  (both bf16 row-major, K=512)
// MODE 0: C[m*512+n] bf16.  MODE 1: C transposed per-batch: C[((m>>10)*512+n)*1024 + (m&1023)]
template <int MODE>
__global__ __launch_bounds__(256) void gemm_bt(const unsigned short* __restrict__ A,
                                               const unsigned short* __restrict__ W,
                                               unsigned short* __restrict__ C) {
  __shared__ unsigned short tA[128 * 64];  // 128 rows x 64 k (128B rows, XOR-swizzled)
  __shared__ unsigned short tB[128 * 64];
  const int tid = threadIdx.x;
  const int lane = tid & 63;
  const int wave = tid >> 6;
  const int m0 = blockIdx.x * 128;
  const int n0 = blockIdx.y * 128;
  const int wm = (wave & 1) * 64;
  const int wn = (wave >> 1) * 64;
  const int r15 = lane & 15, hi = lane >> 4;

  f32x4 acc[4][4];
  for (int i = 0; i < 4; ++i)
    for (int j = 0; j < 4; ++j) acc[i][j] = (f32x4){0.f, 0.f, 0.f, 0.f};

  for (int kt = 0; kt < 8; ++kt) {
    const int k0 = kt * 64;
    // stage: 128 rows x 64 bf16 each tile; 256 threads x 4 iters x 16B
    for (int it = 0; it < 4; ++it) {
      int idx = it * 256 + tid;
      int row = idx >> 3, c = idx & 7;
      int cs = c ^ (row & 7);
      short8 va = *(const short8*)(A + (size_t)(m0 + row) * 512 + k0 + c * 8);
      *(short8*)&tA[row * 64 + cs * 8] = va;
      short8 vb = *(const short8*)(W + (size_t)(n0 + row) * 512 + k0 + c * 8);
      *(short8*)&tB[row * 64 + cs * 8] = vb;
    }
    __syncthreads();
    short8 af[2][4], bf[2][4];
    for (int kk = 0; kk < 2; ++kk) {
      for (int mi = 0; mi < 4; ++mi) {
        int row = wm + mi * 16 + r15;
        int ch = kk * 4 + hi;
        af[kk][mi] = *(short8*)&tA[row * 64 + (ch ^ (row & 7)) * 8];
      }
      for (int ni = 0; ni < 4; ++ni) {
        int row = wn + ni * 16 + r15;
        int ch = kk * 4 + hi;
        bf[kk][ni] = *(short8*)&tB[row * 64 + (ch ^ (row & 7)) * 8];
      }
      for (int mi = 0; mi < 4; ++mi)
        for (int ni = 0; ni < 4; ++ni)
          acc[mi][ni] = __builtin_amdgcn_mfma_f32_16x16x32_bf16(
              af[kk][mi], bf[kk][ni], acc[mi][ni], 0, 0, 0);
    }
    __syncthreads();
  }
  for (int mi = 0; mi < 4; ++mi) {
    for (int ni = 0; ni < 4; ++ni) {
      for (int r = 0; r < 4; ++r) {
        int m = m0 + wm + mi * 16 + hi * 4 + r;
        int n = n0 + wn + ni * 16 + r15;
        unsigned short v = f2b(acc[mi][ni][r]);
        if (MODE == 0) {
          C[(size_t)m * 512 + n] = v;
        } else {
          C[((size_t)(m >> 10) * 512 + n) * 1024 + (size_t)(m & 1023)] = v;
        }
      }
    }
  }
}

// ---------------- K2: scores + mask + softmax + query_mask -> attn (f32, into d_out)
__global__ __launch_bounds__(512) void attn_kernel(const unsigned short* __restrict__ Qp,
                                                   const unsigned short* __restrict__ Kp,
                                                   const int* __restrict__ mask,
                                                   const float* __restrict__ qmask,
                                                   float* __restrict__ attn) {
  __shared__ unsigned short tQ[16 * 128];  // 16 q-rows x 128 d (256B rows, swizzled)
  __shared__ float S[16][1024];            // 64KB score buffer
  const int qt = blockIdx.x, h = blockIdx.y, b = blockIdx.z;
  const int q0 = qt * 16;
  const int tid = threadIdx.x;
  const int lane = tid & 63, wave = tid >> 6;
  const int r15 = lane & 15, hi = lane >> 4;

  if (tid < 256) {
    int row = tid >> 4, c = tid & 15;
    short8 v = *(const short8*)(Qp + (size_t)(b * NSQ + q0 + row) * NHID + h * NDH + c * 8);
    int cs = c ^ (row & 7);
    *(short8*)&tQ[row * 128 + cs * 8] = v;
  }
  __syncthreads();

  // Q fragments (shared across all k-fragments): k-window = d dimension
  short8 aq[4];
  for (int ks = 0; ks < 4; ++ks) {
    int ch = ks * 4 + hi;
    aq[ks] = *(short8*)&tQ[r15 * 128 + ((ch ^ (r15 & 7)) * 8)];
  }

  f32x4 acc[8];
  for (int f = 0; f < 8; ++f) acc[f] = (f32x4){0.f, 0.f, 0.f, 0.f};
  const int kbase = wave * 128;  // each wave owns 128 k-columns
  const unsigned short* kb = Kp + (size_t)b * NSK * NHID + h * NDH + hi * 8;
  for (int f = 0; f < 8; ++f) {
    int kcol = kbase + f * 16 + r15;
    const unsigned short* kptr = kb + (size_t)kcol * NHID;
    for (int ks = 0; ks < 4; ++ks) {
      short8 bk = *(const short8*)(kptr + ks * 32);
      acc[f] = __builtin_amdgcn_mfma_f32_16x16x32_bf16(aq[ks], bk, acc[f], 0, 0, 0);
    }
  }
  for (int f = 0; f < 8; ++f)
    for (int r = 0; r < 4; ++r)
      S[hi * 4 + r][kbase + f * 16 + r15] = acc[f][r];
  __syncthreads();

  const float isd = 0.08838834764831845f;  // 1/sqrt(128)
  for (int rr = 0; rr < 2; ++rr) {
    int r = wave * 2 + rr;
    int q = q0 + r;
    const int* mrow = mask + ((size_t)b * NSQ + q) * NSK;
    float sv[16];
    float mx = -3.4e38f;
    for (int j = 0; j < 16; ++j) {
      int k = lane + j * 64;
      float s = S[r][k] * isd;
      s = mrow[k] ? -4294967296.0f : s;  // MASK_FILL = -2^32+1 rounds to -2^32 in f32
      sv[j] = s;
      mx = fmaxf(mx, s);
    }
    for (int off = 32; off > 0; off >>= 1) mx = fmaxf(mx, __shfl_xor(mx, off));
    float sum = 0.f;
    for (int j = 0; j < 16; ++j) {
      float e = __expf(sv[j] - mx);
      sv[j] = e;
      sum += e;
    }
    for (int off = 32; off > 0; off >>= 1) sum += __shfl_xor(sum, off);
    float scl = qmask[b * NSQ + q] / sum;
    float* orow = attn + ((size_t)(h * NB + b) * NSQ + q) * NSK;
    for (int j = 0; j < 16; ++j) orow[lane + j * 64] = sv[j] * scl;
  }
}

// ---------------- K3: out = attn @ V, +residual, LayerNorm -> result (f32)
__global__ __launch_bounds__(512) void pv_ln_kernel(const float* __restrict__ attn,
                                                    const unsigned short* __restrict__ Vt,
                                                    const float* __restrict__ dec,
                                                    const float* __restrict__ gamma,
                                                    const float* __restrict__ beta,
                                                    float* __restrict__ result) {
  __shared__ float xb[32][512];  // 64KB residual buffer
  const int qt = blockIdx.x, b = blockIdx.y;
  const int q0 = qt * 32;
  const int tid = threadIdx.x;
  const int lane = tid & 63, wave = tid >> 6;
  const int wq = wave & 1, h = wave >> 1;  // wave -> (q-half, head)
  const int r15 = lane & 15, hi = lane >> 4;

  f32x4 acc[8];
  for (int f = 0; f < 8; ++f) acc[f] = (f32x4){0.f, 0.f, 0.f, 0.f};
  const float* arow =
      attn + ((size_t)(h * NB + b) * NSQ + q0 + wq * 16 + r15) * NSK + hi * 8;
  const unsigned short* vb = Vt + (size_t)(b * NHID + h * NDH) * NSK + hi * 8;
  for (int kt = 0; kt < 32; ++kt) {
    const float* ap = arow + kt * 32;
    float4 a0 = *(const float4*)ap;
    float4 a1 = *(const float4*)(ap + 4);
    short8 af;
    af[0] = (short)f2b(a0.x); af[1] = (short)f2b(a0.y);
    af[2] = (short)f2b(a0.z); af[3] = (short)f2b(a0.w);
    af[4] = (short)f2b(a1.x); af[5] = (short)f2b(a1.y);
    af[6] = (short)f2b(a1.z); af[7] = (short)f2b(a1.w);
    for (int f = 0; f < 8; ++f) {
      short8 bv = *(const short8*)(vb + (size_t)(f * 16 + r15) * NSK + kt * 32);
      acc[f] = __builtin_amdgcn_mfma_f32_16x16x32_bf16(af, bv, acc[f], 0, 0, 0);
    }
  }
  for (int f = 0; f < 8; ++f) {
    for (int r = 0; r < 4; ++r) {
      int ql = wq * 16 + hi * 4 + r;
      int c = h * NDH + f * 16 + r15;
      float x = acc[f][r] + dec[(size_t)(b * NSQ + q0 + ql) * NHID + c];
      xb[ql][c] = x;
    }
  }
  __syncthreads();
  for (int rr = 0; rr < 4; ++rr) {
    int r = wave * 4 + rr;
    float v[8];
    float s = 0.f;
    for (int j = 0; j < 8; ++j) {
      v[j] = xb[r][lane + j * 64];
      s += v[j];
    }
    for (int off = 32; off > 0; off >>= 1) s += __shfl_xor(s, off);
    float mu = s * (1.f / 512.f);
    float s2 = 0.f;
    for (int j = 0; j < 8; ++j) {
      float d = v[j] - mu;
      s2 += d * d;
    }
    for (int off = 32; off > 0; off >>= 1) s2 += __shfl_xor(s2, off);
    float rstd = rsqrtf(s2 * (1.f / 512.f) + 1e-5f);
    float* out = result + (size_t)(b * NSQ + q0 + r) * NHID;
    for (int j = 0; j < 8; ++j) {
      int c = lane + j * 64;
      out[c] = (v[j] - mu) * rstd * gamma[c] + beta[c];
    }
  }
}

extern "C" void kernel_launch(void* const* d_in, const int* in_sizes, int n_in,
                              void* d_out, int out_size, void* d_ws, size_t ws_size,
                              hipStream_t stream) {
  const float* memory = (const float*)d_in[0];
  const float* dec = (const float*)d_in[1];
  const int* mask = (const int*)d_in[2];  // bool input, assumed int32 on device
  const float* qmask = (const float*)d_in[3];
  const float* Wk = (const float*)d_in[4];
  const float* Wv = (const float*)d_in[5];
  const float* Wq = (const float*)d_in[6];
  const float* gamma = (const float*)d_in[7];
  const float* beta = (const float*)d_in[8];

  char* ws = (char*)d_ws;
  unsigned short* memB = (unsigned short*)(ws + 0);         // 8  MB
  unsigned short* decB = (unsigned short*)(ws + 8388608);   // 8  MB
  unsigned short* WkB = (unsigned short*)(ws + 16777216);   // .5 MB
  unsigned short* WvB = (unsigned short*)(ws + 17301504);   // .5 MB
  unsigned short* WqB = (unsigned short*)(ws + 17825792);   // .5 MB
  unsigned short* Kp = (unsigned short*)(ws + 18350080);    // 8  MB  [b,s,o]
  unsigned short* Qp = (unsigned short*)(ws + 26738688);    // 8  MB  [b,s,o]
  unsigned short* Vt = (unsigned short*)(ws + 35127296);    // 8  MB  [b,o,s]

  float* resultp = (float*)d_out;            // (B,SQ,H)    = 4194304 f32
  float* attnp = resultp + 4194304;          // (NH*B,SQ,SK)= 33554432 f32

  cvt_kernel<<<dim3(2048), dim3(256), 0, stream>>>(memory, memB, 4194304);
  cvt_kernel<<<dim3(2048), dim3(256), 0, stream>>>(dec, decB, 4194304);
  cvt_kernel<<<dim3(128), dim3(256), 0, stream>>>(Wk, WkB, 262144);
  cvt_kernel<<<dim3(128), dim3(256), 0, stream>>>(Wv, WvB, 262144);
  cvt_kernel<<<dim3(128), dim3(256), 0, stream>>>(Wq, WqB, 262144);

  gemm_bt<0><<<dim3(64, 4), dim3(256), 0, stream>>>(decB, WqB, Qp);
  gemm_bt<0><<<dim3(64, 4), dim3(256), 0, stream>>>(memB, WkB, Kp);
  gemm_bt<1><<<dim3(64, 4), dim3(256), 0, stream>>>(memB, WvB, Vt);

  attn_kernel<<<dim3(64, 4, 8), dim3(512), 0, stream>>>(Qp, Kp, mask, qmask, attnp);
  pv_ln_kernel<<<dim3(32, 8), dim3(512), 0, stream>>>(attnp, Vt, dec, gamma, beta, resultp);
}